// Round 6
// baseline (125.261 us; speedup 1.0000x reference)
//
#include <hip/hip_runtime.h>
#include <math.h>

#define H 128
#define MROWS 64           // node rows per MLP block
#define XS 136             // padded row stride (ushorts) for bf16 LDS tiles

typedef __attribute__((ext_vector_type(8))) short short8;
typedef __attribute__((ext_vector_type(4))) float floatx4;

__device__ __forceinline__ unsigned short f2bf(float f) {
    unsigned u = __float_as_uint(f);
    return (unsigned short)((u + 0x7FFFu + ((u >> 16) & 1u)) >> 16);  // RNE
}
__device__ __forceinline__ unsigned pack2bf(float lo, float hi) {
    return (unsigned)f2bf(lo) | ((unsigned)f2bf(hi) << 16);
}

// stage a 128x128 fp32 weight matrix into padded bf16 LDS tile
__device__ __forceinline__ void stage_w(const float* __restrict__ W,
                                        unsigned short* __restrict__ Wl, int tid) {
    const float4* src = (const float4*)W;
    #pragma unroll
    for (int i = 0; i < 8; ++i) {
        int cc = i * 256 + tid;                   // 2048 chunks of 8 ushorts
        int row = cc >> 4, c = cc & 15;
        float4 f0 = src[cc * 2], f1 = src[cc * 2 + 1];
        uint4 pk;
        pk.x = pack2bf(f0.x, f0.y);
        pk.y = pack2bf(f0.z, f0.w);
        pk.z = pack2bf(f1.x, f1.y);
        pk.w = pack2bf(f1.z, f1.w);
        *(uint4*)(Wl + row * XS + c * 8) = pk;
    }
}

// ---------------------------------------------------------------------------
// Kernel 1: g = mlp(emb); write per-row-quantized int8 of normalize(g)
// plus per-row fp32 scale.  MFMA 16x16x32 bf16, 256 thr / 64 rows per block.
// Weight fp32->bf16 conversion fused into LDS staging (no prep kernel).
// ---------------------------------------------------------------------------
__global__ __launch_bounds__(256, 2) void mlp_mfma(
    const float* __restrict__ emb,
    const float* __restrict__ W1, const float* __restrict__ b1,
    const float* __restrict__ W2, const float* __restrict__ b2,
    signed char* __restrict__ qtab, float* __restrict__ scl, int N)
{
    __shared__ unsigned short Wl[H * XS];         // 34 KB, W1 then W2 (padded)
    __shared__ char dbuf[2 * MROWS * XS * 2];     // xs|hs (bf16), overlaid by gs (fp32)
    __shared__ float invn_s[MROWS];
    __shared__ float amax_s[MROWS];

    unsigned short* xs = (unsigned short*)dbuf;   // [MROWS][XS]
    unsigned short* hs = xs + MROWS * XS;         // [MROWS][XS]
    float*          gs = (float*)dbuf;            // [MROWS][H] overlays xs+hs

    const int tid   = threadIdx.x;
    const int wave  = tid >> 6, lane = tid & 63;
    const int quad  = lane >> 4, l15 = lane & 15;
    const int node0 = blockIdx.x * MROWS;

    // ---- stage W1 (fp32 -> bf16, row-padded) ----
    stage_w(W1, Wl, tid);

    // ---- stage x rows (fp32 -> bf16, row-padded) ----
    #pragma unroll
    for (int i = 0; i < 8; ++i) {
        int flat = i * 1024 + tid * 4;            // logical [64][128]
        int rowl = flat >> 7, col = flat & 127;
        float4 v = make_float4(0.f, 0.f, 0.f, 0.f);
        if (node0 + rowl < N)
            v = *(const float4*)(emb + (size_t)(node0 + rowl) * H + col);
        ushort4 b;
        b.x = f2bf(v.x); b.y = f2bf(v.y); b.z = f2bf(v.z); b.w = f2bf(v.w);
        *(ushort4*)(xs + rowl * XS + col) = b;
    }
    __syncthreads();

    short8 afr[4];
    const int mrow = wave * 16 + l15;

    // ---- layer 1: hs = elu(x @ W1^T + b1) ----
    #pragma unroll
    for (int ks = 0; ks < 4; ++ks)
        afr[ks] = *(const short8*)(xs + mrow * XS + ks * 32 + quad * 8);
    #pragma unroll
    for (int nt = 0; nt < 8; ++nt) {
        floatx4 acc = {0.f, 0.f, 0.f, 0.f};
        #pragma unroll
        for (int ks = 0; ks < 4; ++ks) {
            short8 bfr = *(const short8*)(Wl + (nt * 16 + l15) * XS + ks * 32 + quad * 8);
            acc = __builtin_amdgcn_mfma_f32_16x16x32_bf16(afr[ks], bfr, acc, 0, 0, 0);
        }
        const int col = nt * 16 + l15;
        const float bb = b1[col];
        #pragma unroll
        for (int r = 0; r < 4; ++r) {
            float v = acc[r] + bb;
            v = v > 0.f ? v : (__expf(v) - 1.f);  // ELU
            hs[(wave * 16 + quad * 4 + r) * XS + col] = f2bf(v);
        }
    }
    __syncthreads();                              // hs done; W1/xs reads done

    // ---- stage W2 over W1 (fp32 -> bf16) ----
    stage_w(W2, Wl, tid);
    __syncthreads();

    // ---- layer 2: g = h @ W2^T + b2, fused row sum-sq and max-abs ----
    #pragma unroll
    for (int ks = 0; ks < 4; ++ks)
        afr[ks] = *(const short8*)(hs + mrow * XS + ks * 32 + quad * 8);
    __syncthreads();                              // A-frags in regs -> gs may overwrite xs/hs

    float sq[4] = {0.f, 0.f, 0.f, 0.f};
    float am[4] = {0.f, 0.f, 0.f, 0.f};
    #pragma unroll
    for (int nt = 0; nt < 8; ++nt) {
        floatx4 acc = {0.f, 0.f, 0.f, 0.f};
        #pragma unroll
        for (int ks = 0; ks < 4; ++ks) {
            short8 bfr = *(const short8*)(Wl + (nt * 16 + l15) * XS + ks * 32 + quad * 8);
            acc = __builtin_amdgcn_mfma_f32_16x16x32_bf16(afr[ks], bfr, acc, 0, 0, 0);
        }
        const int col = nt * 16 + l15;
        const float bb = b2[col];
        #pragma unroll
        for (int r = 0; r < 4; ++r) {
            float v = acc[r] + bb;
            gs[(wave * 16 + quad * 4 + r) * H + col] = v;
            sq[r] += v * v;
            am[r] = fmaxf(am[r], fabsf(v));
        }
    }
    // per-row reductions across the 16 lanes of each quad group
    #pragma unroll
    for (int r = 0; r < 4; ++r) {
        float s = sq[r], a = am[r];
        #pragma unroll
        for (int m = 8; m; m >>= 1) {
            s += __shfl_xor(s, m);
            a = fmaxf(a, __shfl_xor(a, m));
        }
        if (l15 == 0) {
            const int row = wave * 16 + quad * 4 + r;
            float nn = sqrtf(s);
            if (nn < 1e-8f) nn = 1e-8f;
            invn_s[row] = 1.f / nn;
            amax_s[row] = fmaxf(a, 1e-20f);
        }
    }
    __syncthreads();

    // ---- per-row scale (quant step of the normalized row) ----
    if (tid < MROWS && node0 + tid < N)
        scl[node0 + tid] = amax_s[tid] * invn_s[tid] * (1.f / 127.f);

    // ---- int8 quantized store: q = round(g * 127 / rowmax) ----
    // 64 rows x 128 int8 = 512 chunks of 16 B; 8 chunks per row.
    #pragma unroll
    for (int i = 0; i < 2; ++i) {
        int chunk = i * 256 + tid;
        int row = chunk >> 3, c0 = (chunk & 7) * 16;
        if (node0 + row < N) {
            const float qs = 127.f / amax_s[row];
            unsigned u[4];
            #pragma unroll
            for (int w = 0; w < 4; ++w) {
                unsigned pk = 0;
                #pragma unroll
                for (int j = 0; j < 4; ++j) {
                    float v = gs[row * H + c0 + w * 4 + j] * qs;
                    int q = (int)rintf(v);
                    q = q > 127 ? 127 : (q < -127 ? -127 : q);
                    pk |= ((unsigned)(q & 255)) << (8 * j);
                }
                u[w] = pk;
            }
            *(uint4*)(qtab + (size_t)(node0 + row) * H + c0) =
                make_uint4(u[0], u[1], u[2], u[3]);
        }
    }
}

// ---------------------------------------------------------------------------
// Kernel 2: out[e] = (q[col] . q[row]) * scl[col] * scl[row]
// 8 lanes per edge, 16 int8 per lane per row (128 B rows).
// Streamed data (ei, out) uses nontemporal hints to keep L2 for qtab.
// ---------------------------------------------------------------------------
__device__ __forceinline__ int dot4acc(unsigned a, unsigned b, int s) {
#if __has_builtin(__builtin_amdgcn_sdot4)
    return __builtin_amdgcn_sdot4((int)a, (int)b, s, false);
#else
    #pragma unroll
    for (int j = 0; j < 4; ++j)
        s += (int)((signed char)(a >> (8 * j))) * (int)((signed char)(b >> (8 * j)));
    return s;
#endif
}

__global__ __launch_bounds__(256) void edge_cos(
    const int* __restrict__ ei, const signed char* __restrict__ qtab,
    const float* __restrict__ scl, float* __restrict__ out, int E)
{
    const int gid = blockIdx.x * 256 + threadIdx.x;
    const int e = gid >> 3, sub = gid & 7;
    if (e >= E) return;

    const int c = __builtin_nontemporal_load(&ei[e]);
    const int r = __builtin_nontemporal_load(&ei[e + E]);

    const uint4 ua = *(const uint4*)(qtab + (size_t)c * H + sub * 16);
    const uint4 ub = *(const uint4*)(qtab + (size_t)r * H + sub * 16);
    int s = 0;
    s = dot4acc(ua.x, ub.x, s);
    s = dot4acc(ua.y, ub.y, s);
    s = dot4acc(ua.z, ub.z, s);
    s = dot4acc(ua.w, ub.w, s);

    #pragma unroll
    for (int m = 4; m; m >>= 1) s += __shfl_xor(s, m);
    if (sub == 0) {
        float v = (float)s * scl[c] * scl[r];
        __builtin_nontemporal_store(v, &out[e]);
    }
}

// ---------------------------------------------------------------------------
extern "C" void kernel_launch(void* const* d_in, const int* in_sizes, int n_in,
                              void* d_out, int out_size, void* d_ws, size_t ws_size,
                              hipStream_t stream) {
    const float* emb = (const float*)d_in[0];
    const int*   ei  = (const int*)d_in[1];
    const float* W1  = (const float*)d_in[2];
    const float* b1  = (const float*)d_in[3];
    const float* W2  = (const float*)d_in[4];
    const float* b2  = (const float*)d_in[5];
    float*       out = (float*)d_out;

    const int N = in_sizes[0] / H;
    const int E = in_sizes[1] / 2;

    signed char* qtab = (signed char*)d_ws;                 // N*H int8
    float*       scl  = (float*)(qtab + (size_t)N * H);     // N fp32

    mlp_mfma<<<(N + MROWS - 1) / MROWS, 256, 0, stream>>>(
        emb, W1, b1, W2, b2, qtab, scl, N);
    edge_cos<<<(E * 8 + 255) / 256, 256, 0, stream>>>(ei, qtab, scl, out, E);
}

// Round 7
// 124.320 us; speedup vs baseline: 1.0076x; 1.0076x over previous
//
#include <hip/hip_runtime.h>
#include <math.h>

#define H 128
#define MROWS 64           // node rows per MLP block
#define XS 136             // padded row stride (ushorts) for bf16 LDS tiles
#define GS 132             // padded row stride (floats) for gs overlay

typedef __attribute__((ext_vector_type(8))) short short8;
typedef __attribute__((ext_vector_type(4))) float floatx4;

__device__ __forceinline__ unsigned short f2bf(float f) {
    unsigned u = __float_as_uint(f);
    return (unsigned short)((u + 0x7FFFu + ((u >> 16) & 1u)) >> 16);  // RNE
}

// ---------------------------------------------------------------------------
// Kernel 0: convert W1,W2 (fp32) to bf16 once. Wbf[0..16383]=W1, [16384..]=W2
// ---------------------------------------------------------------------------
__global__ void prep_weights(const float* __restrict__ W1,
                             const float* __restrict__ W2,
                             unsigned short* __restrict__ Wbf) {
    int i = blockIdx.x * 256 + threadIdx.x;       // 32768 total
    if (i < 16384)       Wbf[i] = f2bf(W1[i]);
    else if (i < 32768)  Wbf[i] = f2bf(W2[i - 16384]);
}

// ---------------------------------------------------------------------------
// Kernel 1: g = mlp(emb); per-row int8 quant of normalize(g) + fp32 scale.
// MFMA 16x16x32 bf16. 256 thr / 64 rows per block, 3 blocks/CU (52 KB LDS).
// Layer-1 A-fragments load straight from global (no xs tile); gs overlays Wl.
// ---------------------------------------------------------------------------
__global__ __launch_bounds__(256, 3) void mlp_mfma(
    const float* __restrict__ emb, const unsigned short* __restrict__ Wbf,
    const float* __restrict__ b1, const float* __restrict__ b2,
    signed char* __restrict__ qtab, float* __restrict__ scl, int N)
{
    __shared__ unsigned short Wl[H * XS];         // 34 KB: W1, then W2, then gs overlay
    __shared__ unsigned short hs[MROWS * XS];     // 17.4 KB hidden rows (bf16)
    __shared__ float amax_s[MROWS];
    float* gs = (float*)Wl;                       // [MROWS][GS] fp32 overlay

    const int tid   = threadIdx.x;
    const int wave  = tid >> 6, lane = tid & 63;
    const int quad  = lane >> 4, l15 = lane & 15;
    const int node0 = blockIdx.x * MROWS;
    const int mrow_g = node0 + wave * 16 + l15;   // this lane's A-frag row (global)

    // ---- layer-1 A-fragments straight from global (fp32 -> bf16 in regs) ----
    short8 afr[4];
    #pragma unroll
    for (int ks = 0; ks < 4; ++ks) {
        float4 f0 = make_float4(0.f, 0.f, 0.f, 0.f), f1 = f0;
        if (mrow_g < N) {
            const float* p = emb + (size_t)mrow_g * H + ks * 32 + quad * 8;
            f0 = *(const float4*)p;
            f1 = *(const float4*)(p + 4);
        }
        short8 a;
        a[0] = f2bf(f0.x); a[1] = f2bf(f0.y); a[2] = f2bf(f0.z); a[3] = f2bf(f0.w);
        a[4] = f2bf(f1.x); a[5] = f2bf(f1.y); a[6] = f2bf(f1.z); a[7] = f2bf(f1.w);
        afr[ks] = a;
    }

    // ---- stage W1 (bf16, row-padded): 2048 chunks of 8 ushorts ----
    {
        const float4* src = (const float4*)Wbf;
        #pragma unroll
        for (int i = 0; i < 8; ++i) {
            int cc = i * 256 + tid;
            int row = cc >> 4, c = cc & 15;
            *(float4*)(Wl + row * XS + c * 8) = src[cc];
        }
    }
    __syncthreads();

    // ---- layer 1: hs = elu(x @ W1^T + b1) ----
    #pragma unroll
    for (int nt = 0; nt < 8; ++nt) {
        floatx4 acc = {0.f, 0.f, 0.f, 0.f};
        #pragma unroll
        for (int ks = 0; ks < 4; ++ks) {
            short8 bfr = *(const short8*)(Wl + (nt * 16 + l15) * XS + ks * 32 + quad * 8);
            acc = __builtin_amdgcn_mfma_f32_16x16x32_bf16(afr[ks], bfr, acc, 0, 0, 0);
        }
        const int col = nt * 16 + l15;
        const float bb = b1[col];
        #pragma unroll
        for (int r = 0; r < 4; ++r) {
            float v = acc[r] + bb;
            v = v > 0.f ? v : (__expf(v) - 1.f);  // ELU
            hs[(wave * 16 + quad * 4 + r) * XS + col] = f2bf(v);
        }
    }
    __syncthreads();                              // hs complete; W1 reads complete

    // ---- stage W2 over W1; load layer-2 A-frags from hs ----
    {
        const float4* src = (const float4*)(Wbf + 16384);
        #pragma unroll
        for (int i = 0; i < 8; ++i) {
            int cc = i * 256 + tid;
            int row = cc >> 4, c = cc & 15;
            *(float4*)(Wl + row * XS + c * 8) = src[cc];
        }
    }
    #pragma unroll
    for (int ks = 0; ks < 4; ++ks)
        afr[ks] = *(const short8*)(hs + (wave * 16 + l15) * XS + ks * 32 + quad * 8);
    __syncthreads();                              // W2 staged

    // ---- layer 2: acc2 = h @ W2^T + b2 (kept in registers) ----
    floatx4 acc2[8];
    #pragma unroll
    for (int nt = 0; nt < 8; ++nt) {
        floatx4 acc = {0.f, 0.f, 0.f, 0.f};
        #pragma unroll
        for (int ks = 0; ks < 4; ++ks) {
            short8 bfr = *(const short8*)(Wl + (nt * 16 + l15) * XS + ks * 32 + quad * 8);
            acc = __builtin_amdgcn_mfma_f32_16x16x32_bf16(afr[ks], bfr, acc, 0, 0, 0);
        }
        const float bb = b2[nt * 16 + l15];
        #pragma unroll
        for (int r = 0; r < 4; ++r) acc[r] += bb;
        acc2[nt] = acc;
    }

    // ---- per-row sum-sq / max-abs: in-register over nt, shuffle over 16 lanes ----
    float sq[4] = {0.f, 0.f, 0.f, 0.f};
    float am[4] = {0.f, 0.f, 0.f, 0.f};
    #pragma unroll
    for (int nt = 0; nt < 8; ++nt)
        #pragma unroll
        for (int r = 0; r < 4; ++r) {
            float v = acc2[nt][r];
            sq[r] += v * v;
            am[r] = fmaxf(am[r], fabsf(v));
        }
    #pragma unroll
    for (int r = 0; r < 4; ++r) {
        #pragma unroll
        for (int m = 8; m; m >>= 1) {
            sq[r] += __shfl_xor(sq[r], m);
            am[r] = fmaxf(am[r], __shfl_xor(am[r], m));
        }
        am[r] = fmaxf(am[r], 1e-20f);
        if (l15 == 0) {
            const int grow = node0 + wave * 16 + quad * 4 + r;
            amax_s[wave * 16 + quad * 4 + r] = am[r];
            if (grow < N) {
                float nn = sqrtf(sq[r]);
                if (nn < 1e-8f) nn = 1e-8f;
                scl[grow] = am[r] / (127.f * nn);
            }
        }
    }
    __syncthreads();                              // all W2 reads done -> Wl reusable as gs

    // ---- spill acc2 to gs (padded fp32) for coalesced quant store ----
    #pragma unroll
    for (int nt = 0; nt < 8; ++nt) {
        const int col = nt * 16 + l15;
        #pragma unroll
        for (int r = 0; r < 4; ++r)
            gs[(wave * 16 + quad * 4 + r) * GS + col] = acc2[nt][r];
    }
    __syncthreads();

    // ---- int8 quantized store: q = round(g * 127 / rowmax) ----
    #pragma unroll
    for (int i = 0; i < 2; ++i) {
        int chunk = i * 256 + tid;                // 512 chunks of 16 B; 8 per row
        int row = chunk >> 3, c0 = (chunk & 7) * 16;
        if (node0 + row < N) {
            const float qs = 127.f / amax_s[row];
            unsigned u[4];
            #pragma unroll
            for (int w = 0; w < 4; ++w) {
                unsigned pk = 0;
                #pragma unroll
                for (int j = 0; j < 4; ++j) {
                    float v = gs[row * GS + c0 + w * 4 + j] * qs;
                    int q = (int)rintf(v);
                    q = q > 127 ? 127 : (q < -127 ? -127 : q);
                    pk |= ((unsigned)(q & 255)) << (8 * j);
                }
                u[w] = pk;
            }
            *(uint4*)(qtab + (size_t)(node0 + row) * H + c0) =
                make_uint4(u[0], u[1], u[2], u[3]);
        }
    }
}

// ---------------------------------------------------------------------------
// Kernel 2: out[e] = (q[col] . q[row]) * scl[col] * scl[row]
// 8 lanes per edge, 16 int8 per lane per row (128 B rows).
// ---------------------------------------------------------------------------
__device__ __forceinline__ int dot4acc(unsigned a, unsigned b, int s) {
#if __has_builtin(__builtin_amdgcn_sdot4)
    return __builtin_amdgcn_sdot4((int)a, (int)b, s, false);
#else
    #pragma unroll
    for (int j = 0; j < 4; ++j)
        s += (int)((signed char)(a >> (8 * j))) * (int)((signed char)(b >> (8 * j)));
    return s;
#endif
}

__global__ __launch_bounds__(256) void edge_cos(
    const int* __restrict__ ei, const signed char* __restrict__ qtab,
    const float* __restrict__ scl, float* __restrict__ out, int E)
{
    const int gid = blockIdx.x * 256 + threadIdx.x;
    const int e = gid >> 3, sub = gid & 7;
    if (e >= E) return;

    const int c = __builtin_nontemporal_load(&ei[e]);
    const int r = __builtin_nontemporal_load(&ei[e + E]);

    const uint4 ua = *(const uint4*)(qtab + (size_t)c * H + sub * 16);
    const uint4 ub = *(const uint4*)(qtab + (size_t)r * H + sub * 16);
    int s = 0;
    s = dot4acc(ua.x, ub.x, s);
    s = dot4acc(ua.y, ub.y, s);
    s = dot4acc(ua.z, ub.z, s);
    s = dot4acc(ua.w, ub.w, s);

    #pragma unroll
    for (int m = 4; m; m >>= 1) s += __shfl_xor(s, m);
    if (sub == 0) {
        float v = (float)s * scl[c] * scl[r];
        __builtin_nontemporal_store(v, &out[e]);
    }
}

// ---------------------------------------------------------------------------
extern "C" void kernel_launch(void* const* d_in, const int* in_sizes, int n_in,
                              void* d_out, int out_size, void* d_ws, size_t ws_size,
                              hipStream_t stream) {
    const float* emb = (const float*)d_in[0];
    const int*   ei  = (const int*)d_in[1];
    const float* W1  = (const float*)d_in[2];
    const float* b1  = (const float*)d_in[3];
    const float* W2  = (const float*)d_in[4];
    const float* b2  = (const float*)d_in[5];
    float*       out = (float*)d_out;

    const int N = in_sizes[0] / H;
    const int E = in_sizes[1] / 2;

    unsigned short* Wbf  = (unsigned short*)d_ws;           // 32768 bf16 = 64 KB
    signed char*    qtab = (signed char*)(Wbf + 32768);     // N*H int8
    float*          scl  = (float*)(qtab + (size_t)N * H);  // N fp32

    prep_weights<<<128, 256, 0, stream>>>(W1, W2, Wbf);
    mlp_mfma<<<(N + MROWS - 1) / MROWS, 256, 0, stream>>>(
        emb, Wbf, b1, b2, qtab, scl, N);
    edge_cos<<<(E * 8 + 255) / 256, 256, 0, stream>>>(ei, qtab, scl, out, E);
}